// Round 1
// 241.136 us; speedup vs baseline: 1.0205x; 1.0205x over previous
//
#include <hip/hip_runtime.h>
#include <hip/hip_fp16.h>

// SignedGCN (2-layer, eval) — dst-sorted segment gather, register accumulation.
// R9: sign-split aggregation across XCDs (blockIdx%8 -> XCD; XCD 0-3 = pos,
// 4-7 = neg) so each XCD's gather table (3.2 MB fp16) fits its 4 MB L2.
// R10: agg_split restructured 16 lanes/node x ushort -> 4 lanes/node x uint2
// (8B loads, 4x fewer VMEM+addr instrs per edge) + v_fma_mix_f32 fused
// f16->f32 convert+accumulate (halves cvt/add VALU). Issue-bound -> ~2.7x
// fewer issue slots per edge.

#define BSHIFT 8
#define BSZ 256
#define MAX_NBK 512
#define FILL_CAP 13056      // max edges per chunk staged in LDS (51 KB)
#define SORT_CAP 12032      // max edges per bucket staged in LDS (47 KB)

__device__ __forceinline__ int chunk_of_block(int bid, int NCH) {
  return (NCH % 8 == 0) ? (bid % 8) * (NCH / 8) + bid / 8 : bid;
}

// ---- build: edges bucketed by dst>>8, then counting-sorted by local dst ----

__global__ __launch_bounds__(256) void bucket_count2(
    const int* __restrict__ eP, const int* __restrict__ eN,
    int E, int CH, int NCH, int NBK, int* __restrict__ ccP, int* __restrict__ ccN) {
  __shared__ int cnt[MAX_NBK];
  const int* dsts = (blockIdx.y ? eN : eP) + E;
  int* cc = blockIdx.y ? ccN : ccP;
  const int c = chunk_of_block(blockIdx.x, NCH);
  for (int i = threadIdx.x; i < NBK; i += 256) cnt[i] = 0;
  __syncthreads();
  int base = c * CH, end = min(E, base + CH);
  for (int idx = base + threadIdx.x; idx < end; idx += 256)
    atomicAdd(&cnt[dsts[idx] >> BSHIFT], 1);
  __syncthreads();
  for (int i = threadIdx.x; i < NBK; i += 256)
    cc[(size_t)c * NBK + i] = cnt[i];
}

__global__ __launch_bounds__(512) void col_scan2(
    int* __restrict__ ccP, int* __restrict__ ccN, int NCH, int NBK,
    int* __restrict__ totP, int* __restrict__ totN) {
  __shared__ int s[512];
  int* cc = blockIdx.y ? ccN : ccP;
  int* tot = blockIdx.y ? totN : totP;
  int b = blockIdx.x, t = threadIdx.x;
  int v = (t < NCH) ? cc[(size_t)t * NBK + b] : 0;
  s[t] = v;
  for (int off = 1; off < 512; off <<= 1) {
    __syncthreads();
    int a = (t >= off) ? s[t - off] : 0;
    __syncthreads();
    s[t] += a;
  }
  __syncthreads();
  if (t < NCH) cc[(size_t)t * NBK + b] = s[t] - v;
  if (t == 511) tot[b] = s[511];
}

__global__ __launch_bounds__(512) void base_scan(
    const int* __restrict__ totP, const int* __restrict__ totN, int NBK,
    int* __restrict__ baseP, int* __restrict__ baseN,
    int* __restrict__ rowP, int* __restrict__ rowN, int n, int E) {
  __shared__ int sp[512], sn[512];
  __shared__ int carryP, carryN;
  int t = threadIdx.x;
  if (t == 0) { carryP = 0; carryN = 0; }
  __syncthreads();
  for (int tile = 0; tile < NBK; tile += 512) {
    int idx = tile + t;
    int vp = (idx < NBK) ? totP[idx] : 0;
    int vn = (idx < NBK) ? totN[idx] : 0;
    sp[t] = vp; sn[t] = vn;
    for (int off = 1; off < 512; off <<= 1) {
      __syncthreads();
      int ap = (t >= off) ? sp[t - off] : 0;
      int an = (t >= off) ? sn[t - off] : 0;
      __syncthreads();
      sp[t] += ap; sn[t] += an;
    }
    __syncthreads();
    if (idx < NBK) {
      baseP[idx] = carryP + sp[t] - vp;
      baseN[idx] = carryN + sn[t] - vn;
    }
    __syncthreads();
    if (t == 0) { carryP += sp[511]; carryN += sn[511]; }
    __syncthreads();
  }
  if (t == 0) {
    baseP[NBK] = E; baseN[NBK] = E;
    rowP[n] = E; rowN[n] = E;
  }
}

__global__ __launch_bounds__(512) void bucket_fill3(
    const int* __restrict__ eP, const int* __restrict__ eN,
    int E, int CH, int NCH, int NBK,
    const int* __restrict__ ccP, const int* __restrict__ ccN,
    const int* __restrict__ totP, const int* __restrict__ totN,
    const int* __restrict__ basP, const int* __restrict__ basN,
    unsigned* __restrict__ prP, unsigned* __restrict__ prN) {
  __shared__ unsigned obuf[FILL_CAP];
  __shared__ int chofs[MAX_NBK], hist[MAX_NBK], lofs[MAX_NBK], cur[MAX_NBK];
  __shared__ int s[512];
  const int* edges = blockIdx.y ? eN : eP;
  const int* cc = blockIdx.y ? ccN : ccP;
  const int* tot = blockIdx.y ? totN : totP;
  const int* bas = blockIdx.y ? basN : basP;
  unsigned* pairs = blockIdx.y ? prN : prP;
  const int c = chunk_of_block(blockIdx.x, NCH);
  const int t = threadIdx.x;

  int h = 0;
  if (t < NBK) {
    int o0 = cc[(size_t)c * NBK + t];
    int o1 = (c + 1 < NCH) ? cc[(size_t)(c + 1) * NBK + t] : tot[t];
    chofs[t] = o0;
    h = o1 - o0;
    hist[t] = h;
  }
  s[t] = h;
  for (int off = 1; off < 512; off <<= 1) {
    __syncthreads();
    int a = (t >= off) ? s[t - off] : 0;
    __syncthreads();
    s[t] += a;
  }
  __syncthreads();
  if (t < NBK) { lofs[t] = s[t] - hist[t]; cur[t] = s[t] - hist[t]; }
  __syncthreads();

  int base = c * CH, end = min(E, base + CH);
  for (int idx = base + t; idx < end; idx += 512) {
    int sv = edges[idx], d = edges[E + idx];
    int b = d >> BSHIFT;
    int pos = atomicAdd(&cur[b], 1);
    obuf[pos] = (unsigned)sv | ((unsigned)(d & (BSZ - 1)) << 24);
  }
  __syncthreads();

  if (t < NBK) {
    int cnt = hist[t], lo = lofs[t];
    unsigned* dst = pairs + (size_t)bas[t] + chofs[t];
    for (int j = 0; j < cnt; ++j) dst[j] = obuf[lo + j];
  }
}

__global__ __launch_bounds__(256) void tile_sort3(
    const unsigned* __restrict__ prP, const unsigned* __restrict__ prN,
    const int* __restrict__ basP, const int* __restrict__ basN, int n,
    float* __restrict__ dinvP, float* __restrict__ dinvN,
    int* __restrict__ rowP, int* __restrict__ rowN,
    unsigned* __restrict__ srcsP, unsigned* __restrict__ srcsN) {
  __shared__ unsigned obuf[SORT_CAP];
  __shared__ int hist[BSZ];
  __shared__ int scn[BSZ];
  __shared__ int cur[BSZ];
  const unsigned* pairs = blockIdx.y ? prN : prP;
  const int* base = blockIdx.y ? basN : basP;
  float* dinv = blockIdx.y ? dinvN : dinvP;
  int* rowoff = blockIdx.y ? rowN : rowP;
  unsigned* srcs = blockIdx.y ? srcsN : srcsP;
  const int b = blockIdx.x, t = threadIdx.x;
  const int s0 = base[b], s1 = base[b + 1], cnt = s1 - s0;
  hist[t] = 0;
  __syncthreads();
  for (int i = s0 + t; i < s1; i += 256)
    atomicAdd(&hist[pairs[i] >> 24], 1);
  __syncthreads();
  scn[t] = hist[t];
  __syncthreads();
  for (int off = 1; off < BSZ; off <<= 1) {
    int v = (t >= off) ? scn[t - off] : 0;
    __syncthreads();
    scn[t] += v;
    __syncthreads();
  }
  {
    int excl = scn[t] - hist[t];
    cur[t] = excl;
    int node = b * BSZ + t;
    if (node < n) {
      rowoff[node] = s0 + excl;
      dinv[node] = rsqrtf(1.0f + (float)hist[t]);
    }
  }
  __syncthreads();
  if (cnt <= SORT_CAP) {
    for (int i = s0 + t; i < s1; i += 256) {
      unsigned p = pairs[i];
      int pos = atomicAdd(&cur[p >> 24], 1);
      obuf[pos] = p & 0xFFFFFFu;
    }
    __syncthreads();
    for (int i = t; i < cnt; i += 256) srcs[s0 + i] = obuf[i];
  } else {
    for (int i = s0 + t; i < s1; i += 256) {
      unsigned p = pairs[i];
      int pos = atomicAdd(&cur[p >> 24], 1);
      srcs[s0 + pos] = p & 0xFFFFFFu;
    }
  }
}

// x: [n,128] @ W{p,n}: [128,16] -> hs{p,n}: [n,16] fp16 (scaled by dinv[i])
__global__ __launch_bounds__(256) void xw1_kernel(
    const float* __restrict__ x, const float* __restrict__ Wp, const float* __restrict__ Wn,
    const float* __restrict__ dinvP, const float* __restrict__ dinvN,
    __half* __restrict__ hp, __half* __restrict__ hn, int n)
{
  __shared__ float xs[16 * 132];
  __shared__ float wp[128 * 16], wn[128 * 16];
  const int tid = threadIdx.x;
  const int rowBase = blockIdx.x * 16;

  for (int idx = tid; idx < 512; idx += 256) {
    ((float4*)wp)[idx] = ((const float4*)Wp)[idx];
    ((float4*)wn)[idx] = ((const float4*)Wn)[idx];
  }
  const int nrows = min(16, n - rowBase);
  for (int idx = tid; idx < nrows * 32; idx += 256) {
    int r = idx >> 5, c4 = idx & 31;
    float4 v = ((const float4*)(x + (size_t)(rowBase + r) * 128))[c4];
    *(float4*)(xs + r * 132 + c4 * 4) = v;
  }
  __syncthreads();

  const int r = tid >> 4, c = tid & 15;
  const int i = rowBase + r;
  if (i < n) {
    float ap = 0.f, an = 0.f;
    #pragma unroll
    for (int k = 0; k < 128; ++k) {
      float xv = xs[r * 132 + k];
      ap += xv * wp[k * 16 + c];
      an += xv * wn[k * 16 + c];
    }
    hp[(size_t)i * 16 + c] = __float2half(ap * dinvP[i]);
    hn[(size_t)i * 16 + c] = __float2half(an * dinvN[i]);
  }
}

// fused f16->f32 convert + accumulate: acc += (float)h  (one VALU op each)
__device__ __forceinline__ void fma_mix2(float& aLo, float& aHi, unsigned h2, float one) {
  asm("v_fma_mix_f32 %0, %2, %3, %0 op_sel:[0,0,0] op_sel_hi:[1,0,0]\n\t"
      "v_fma_mix_f32 %1, %2, %3, %1 op_sel:[1,0,0] op_sel_hi:[1,0,0]"
      : "+v"(aLo), "+v"(aHi)
      : "v"(h2), "v"(one));
}

// 4 lanes per node; each lane owns 4 features (8B of the 32B fp16 row).
// unroll-8, two accumulator chains.
__device__ __forceinline__ void seg_sum4(
    const unsigned* __restrict__ srcs, int e, int e1,
    const __half* __restrict__ tab, int lane4, float one,
    float& f0, float& f1, float& f2, float& f3)
{
  float g0 = 0.f, g1 = 0.f, g2 = 0.f, g3 = 0.f;
  for (; e + 8 <= e1; e += 8) {
    unsigned a[8];
    #pragma unroll
    for (int j = 0; j < 8; ++j) a[j] = srcs[e + j];
    uint2 v[8];
    #pragma unroll
    for (int j = 0; j < 8; ++j)
      v[j] = *(const uint2*)(tab + (size_t)a[j] * 16 + lane4 * 4);
    #pragma unroll
    for (int j = 0; j < 8; j += 2) {
      fma_mix2(f0, f1, v[j].x, one);
      fma_mix2(f2, f3, v[j].y, one);
      fma_mix2(g0, g1, v[j + 1].x, one);
      fma_mix2(g2, g3, v[j + 1].y, one);
    }
  }
  for (; e + 2 <= e1; e += 2) {
    unsigned a0 = srcs[e], a1 = srcs[e + 1];
    uint2 v0 = *(const uint2*)(tab + (size_t)a0 * 16 + lane4 * 4);
    uint2 v1 = *(const uint2*)(tab + (size_t)a1 * 16 + lane4 * 4);
    fma_mix2(f0, f1, v0.x, one);
    fma_mix2(f2, f3, v0.y, one);
    fma_mix2(g0, g1, v1.x, one);
    fma_mix2(g2, g3, v1.y, one);
  }
  if (e < e1) {
    uint2 v = *(const uint2*)(tab + (size_t)srcs[e] * 16 + lane4 * 4);
    fma_mix2(f0, f1, v.x, one);
    fma_mix2(f2, f3, v.y, one);
  }
  f0 += g0; f1 += g1; f2 += g2; f3 += g3;
}

// Sign-split aggregation: blockIdx%8 -> XCD (round-robin heuristic);
// XCDs 0-3 handle pos, 4-7 handle neg -> per-XCD gather table 3.2 MB < 4 MB L2.
// 64 nodes per block (4 lanes x 64 groups). Writes raw dinv*acc (f32).
__global__ __launch_bounds__(256) void agg_split(
    const unsigned* __restrict__ srcP, const int* __restrict__ rowP,
    const unsigned* __restrict__ srcN, const int* __restrict__ rowN,
    const __half* __restrict__ inP, const __half* __restrict__ inN,
    const float* __restrict__ dinvP, const float* __restrict__ dinvN,
    float* __restrict__ tmpP, float* __restrict__ tmpN, int n)
{
  const int gb = blockIdx.x;
  const int xcd = gb & 7;
  const int sign = xcd >> 2;
  const int nblk = (gb >> 3) * 4 + (xcd & 3);
  const int lane4 = threadIdx.x & 3, grp = threadIdx.x >> 2;
  const int i = nblk * 64 + grp;
  if (i >= n) return;

  const unsigned* srcs = sign ? srcN : srcP;
  const int* row = sign ? rowN : rowP;
  const __half* tab = sign ? inN : inP;
  const float* dinv = sign ? dinvN : dinvP;
  float* tmp = sign ? tmpN : tmpP;

  const float one = 1.0f;
  float f0 = 0.f, f1 = 0.f, f2 = 0.f, f3 = 0.f;
  uint2 self = *(const uint2*)(tab + (size_t)i * 16 + lane4 * 4);
  fma_mix2(f0, f1, self.x, one);
  fma_mix2(f2, f3, self.y, one);
  seg_sum4(srcs, row[i], row[i + 1], tab, lane4, one, f0, f1, f2, f3);
  const float d = dinv[i];
  float4 o;
  o.x = f0 * d; o.y = f1 * d; o.z = f2 * d; o.w = f3 * d;
  *(float4*)(tmp + (size_t)i * 16 + lane4 * 4) = o;
}

// layer-1 combine: h = relu(b+tmpP) - relu(b+tmpN); G{p,n} = h*dinv fp16
__global__ __launch_bounds__(256) void combine1(
    const float* __restrict__ tmpP, const float* __restrict__ tmpN,
    const float* __restrict__ bp, const float* __restrict__ bn,
    const float* __restrict__ dinvP, const float* __restrict__ dinvN,
    __half* __restrict__ Gp, __half* __restrict__ Gn, long long total)
{
  long long j = (long long)blockIdx.x * 256 + threadIdx.x;
  if (j >= total) return;
  int i = (int)(j >> 4), lane = (int)(j & 15);
  float ap = bp[lane] + tmpP[j];
  float an = bn[lane] + tmpN[j];
  float h = fmaxf(ap, 0.f) - fmaxf(an, 0.f);
  Gp[j] = __float2half(h * dinvP[i]);
  Gn[j] = __float2half(h * dinvN[i]);
}

// layer-2 epilogue: T already in tmp; W2 GEMM + bias + relu-combine + log_softmax
__global__ __launch_bounds__(256) void final2(
    const float* __restrict__ Up, const float* __restrict__ Un,
    const float* __restrict__ W2p, const float* __restrict__ W2n,
    const float* __restrict__ b2p, const float* __restrict__ b2n,
    float* __restrict__ out, int n)
{
  __shared__ float wp[16 * 32], wn[16 * 32];
  for (int i = threadIdx.x; i < 512; i += 256) { wp[i] = W2p[i]; wn[i] = W2n[i]; }
  __syncthreads();

  const int tid = threadIdx.x;
  const int lane = tid & 15, grp = tid >> 4;
  const int i = blockIdx.x * 16 + grp;
  if (i >= n) return;

  float tp = Up[(size_t)i * 16 + lane];
  float tn = Un[(size_t)i * 16 + lane];

  float ap0 = b2p[lane], ap1 = b2p[lane + 16];
  float an0 = b2n[lane], an1 = b2n[lane + 16];
  #pragma unroll
  for (int k = 0; k < 16; ++k) {
    float tpk = __shfl(tp, k, 16);
    float tnk = __shfl(tn, k, 16);
    ap0 += tpk * wp[k * 32 + lane];
    ap1 += tpk * wp[k * 32 + lane + 16];
    an0 += tnk * wn[k * 32 + lane];
    an1 += tnk * wn[k * 32 + lane + 16];
  }
  float v0 = fmaxf(ap0, 0.f) - fmaxf(an0, 0.f);
  float v1 = fmaxf(ap1, 0.f) - fmaxf(an1, 0.f);
  float m = fmaxf(v0, v1);
  #pragma unroll
  for (int off = 8; off > 0; off >>= 1) m = fmaxf(m, __shfl_xor(m, off, 16));
  float s = __expf(v0 - m) + __expf(v1 - m);
  #pragma unroll
  for (int off = 8; off > 0; off >>= 1) s += __shfl_xor(s, off, 16);
  float ls = __logf(s);
  out[(size_t)i * 32 + lane] = v0 - m - ls;
  out[(size_t)i * 32 + lane + 16] = v1 - m - ls;
}

extern "C" void kernel_launch(void* const* d_in, const int* in_sizes, int n_in,
                              void* d_out, int out_size, void* d_ws, size_t ws_size,
                              hipStream_t stream) {
  const float* x   = (const float*)d_in[0];
  const int*   eP  = (const int*)d_in[1];
  const int*   eN  = (const int*)d_in[2];
  const float* W1p = (const float*)d_in[3];
  const float* b1p = (const float*)d_in[4];
  const float* W1n = (const float*)d_in[5];
  const float* b1n = (const float*)d_in[6];
  const float* W2p = (const float*)d_in[7];
  const float* b2p = (const float*)d_in[8];
  const float* W2n = (const float*)d_in[9];
  const float* b2n = (const float*)d_in[10];
  float* out = (float*)d_out;

  const int HID = in_sizes[4];             // 16
  const int F   = in_sizes[3] / HID;       // 128
  const int n   = in_sizes[0] / F;         // 100000
  const int E   = in_sizes[1] / 2;         // 3,200,000
  (void)out_size; (void)n_in; (void)ws_size;

  const int NBK = (n + BSZ - 1) >> BSHIFT;                 // 391
  const int CH  = (((E + 255) / 256) + 255) & ~255;        // 12544
  const int NCH = (E + CH - 1) / CH;                       // 256

  char* p = (char*)d_ws;
  auto alloc = [&](size_t bytes) { char* r = p; p += (bytes + 255) & ~(size_t)255; return r; };

  int*      ccP   = (int*)alloc((size_t)NCH * NBK * 4);
  int*      ccN   = (int*)alloc((size_t)NCH * NBK * 4);
  int*      totP  = (int*)alloc((size_t)NBK * 4);
  int*      totN  = (int*)alloc((size_t)NBK * 4);
  int*      basP  = (int*)alloc((size_t)(NBK + 1) * 4);
  int*      basN  = (int*)alloc((size_t)(NBK + 1) * 4);
  unsigned* prP   = (unsigned*)alloc((size_t)E * 4);
  unsigned* prN   = (unsigned*)alloc((size_t)E * 4);
  unsigned* srcP  = (unsigned*)alloc((size_t)E * 4);
  unsigned* srcN  = (unsigned*)alloc((size_t)E * 4);
  int*      rowP  = (int*)alloc((size_t)(n + 1) * 4);
  int*      rowN  = (int*)alloc((size_t)(n + 1) * 4);
  float*    dinvP = (float*)alloc((size_t)n * 4);
  float*    dinvN = (float*)alloc((size_t)n * 4);
  __half*   hsP   = (__half*)alloc((size_t)n * 16 * 2);
  __half*   hsN   = (__half*)alloc((size_t)n * 16 * 2);
  __half*   Gp    = (__half*)alloc((size_t)n * 16 * 2);
  __half*   Gn    = (__half*)alloc((size_t)n * 16 * 2);
  float*    tmpP  = (float*)alloc((size_t)n * 16 * 4);
  float*    tmpN  = (float*)alloc((size_t)n * 16 * 4);

  // ---- bucketed, dst-sorted edge build (both signs fused per launch) ----
  hipLaunchKernelGGL(bucket_count2, dim3(NCH, 2), dim3(256), 0, stream,
                     eP, eN, E, CH, NCH, NBK, ccP, ccN);
  hipLaunchKernelGGL(col_scan2, dim3(NBK, 2), dim3(512), 0, stream,
                     ccP, ccN, NCH, NBK, totP, totN);
  hipLaunchKernelGGL(base_scan, dim3(1), dim3(512), 0, stream,
                     totP, totN, NBK, basP, basN, rowP, rowN, n, E);
  hipLaunchKernelGGL(bucket_fill3, dim3(NCH, 2), dim3(512), 0, stream,
                     eP, eN, E, CH, NCH, NBK, ccP, ccN, totP, totN,
                     basP, basN, prP, prN);
  hipLaunchKernelGGL(tile_sort3, dim3(NBK, 2), dim3(256), 0, stream,
                     prP, prN, basP, basN, n, dinvP, dinvN, rowP, rowN, srcP, srcN);

  // grids: xw1/final2 keep 16 rows/block; agg uses 64 nodes/block
  const int NB16 = (n + 15) / 16;                 // 6250
  const int NB64 = (n + 63) / 64;                 // 1563
  const int NBS  = ((NB64 + 3) / 4) * 4;          // 1564
  const int GRID = NBS * 2;                       // 3128 (multiple of 8)

  // ---- layer 1 ----
  hipLaunchKernelGGL(xw1_kernel, dim3(NB16), dim3(256), 0, stream,
                     x, W1p, W1n, dinvP, dinvN, hsP, hsN, n);
  hipLaunchKernelGGL(agg_split, dim3(GRID), dim3(256), 0, stream,
                     srcP, rowP, srcN, rowN, hsP, hsN, dinvP, dinvN, tmpP, tmpN, n);
  hipLaunchKernelGGL(combine1, dim3((int)(((long long)n * 16 + 255) / 256)), dim3(256), 0, stream,
                     tmpP, tmpN, b1p, b1n, dinvP, dinvN, Gp, Gn, (long long)n * 16);

  // ---- layer 2 ----
  hipLaunchKernelGGL(agg_split, dim3(GRID), dim3(256), 0, stream,
                     srcP, rowP, srcN, rowN, Gp, Gn, dinvP, dinvN, tmpP, tmpN, n);
  hipLaunchKernelGGL(final2, dim3(NB16), dim3(256), 0, stream,
                     tmpP, tmpN, W2p, W2n, b2p, b2n, out, n);
}